// Round 15
// baseline (609.497 us; speedup 1.0000x reference)
//
#include <hip/hip_runtime.h>

#define DD 128      // GNN_DIM == NODE_FEAT
#define HDIM 512    // H * D
#define EFEAT 32
#define NHEAD 4

typedef short s16x8 __attribute__((ext_vector_type(8)));
typedef float f32x4 __attribute__((ext_vector_type(4)));

__device__ __forceinline__ float lrelu(float x){ return x > 0.f ? x : 0.2f*x; }

__device__ __forceinline__ unsigned short f2bf(float f){
  unsigned u = __float_as_uint(f);
  unsigned r = (u + 0x7FFFu + ((u >> 16) & 1u)) >> 16;
  return (unsigned short)r;
}
__device__ __forceinline__ float bf2f(unsigned short u){
  return __uint_as_float(((unsigned)u) << 16);
}

__device__ __forceinline__ float waveReduceSum(float v){
  #pragma unroll
  for (int m = 1; m < 64; m <<= 1) v += __shfl_xor(v, m, 64);
  return v;
}
__device__ __forceinline__ float quadReduceSum(float v){
  v += __shfl_xor(v, 1, 64); v += __shfl_xor(v, 2, 64);
  v += __shfl_xor(v, 4, 64); v += __shfl_xor(v, 8, 64);
  return v;
}

// ---------------- CSR build over dst ----------------
__global__ void hist_kernel(const int* __restrict__ dst, int* __restrict__ deg, int E){
  int e = blockIdx.x*blockDim.x + threadIdx.x;
  if (e < E) atomicAdd(&deg[dst[e]], 1);
}

// scan writes BOTH offs and cursor (removes the device-to-device memcpy dispatch)
__global__ void scan_kernel(const int* __restrict__ deg, int* __restrict__ offs,
                            int* __restrict__ cursor, int N){
  __shared__ int s[1024];
  int t = threadIdx.x;
  int chunk = (N + 1023) >> 10;
  int b = t*chunk, e = min(b + chunk, N);
  int sum = 0;
  for (int i = b; i < e; i++) sum += deg[i];
  s[t] = sum;
  __syncthreads();
  for (int d = 1; d < 1024; d <<= 1){
    int x = (t >= d) ? s[t - d] : 0;
    __syncthreads();
    s[t] += x;
    __syncthreads();
  }
  int run = s[t] - sum;
  for (int i = b; i < e; i++){ offs[i] = run; cursor[i] = run; run += deg[i]; }
  if (t == 1023) offs[N] = s[1023];
}

__global__ void scatter_kernel(const int* __restrict__ dst, const int* __restrict__ src,
                               int* __restrict__ cursor, int* __restrict__ csrc,
                               int* __restrict__ posOf, int E){
  int e = blockIdx.x*blockDim.x + threadIdx.x;
  if (e < E){
    int d = dst[e];
    int p = atomicAdd(&cursor[d], 1);
    csrc[p] = src[e];
    posOf[e] = p;
  }
}

// ---------------- merged: edge attrs -> bf16 CSR scatter  +  x -> bf16 ---------
__global__ void eap_bf16_kernel(const float* __restrict__ ea, const int* __restrict__ posOf,
                                unsigned short* __restrict__ eap,
                                const float* __restrict__ x, unsigned short* __restrict__ xbf,
                                int E, int nvec){
  int idx = blockIdx.x*blockDim.x + threadIdx.x;
  int nEap = E*8;
  if (idx < nEap){
    int e = idx >> 3, q = idx & 7;
    int p = posOf[e];
    float4 v = *((const float4*)(ea + (size_t)e*EFEAT) + q);
    ushort4 u = make_ushort4(f2bf(v.x), f2bf(v.y), f2bf(v.z), f2bf(v.w));
    *((ushort4*)(eap + (size_t)p*EFEAT) + q) = u;
  } else {
    int i = idx - nEap;
    if (i >= nvec) return;
    float4 v = *((const float4*)x + i);
    *((ushort4*)xbf + i) = make_ushort4(f2bf(v.x), f2bf(v.y), f2bf(v.z), f2bf(v.w));
  }
}

// ---------------- per-edge attention logits for ALL layers + ea column sums ----
__global__ __launch_bounds__(256) void ale_prep_kernel(
    const unsigned short* __restrict__ eap, const float* __restrict__ we_att,
    float* __restrict__ ale, float* __restrict__ ea_sum, int E, int L){
  __shared__ float sea[256][33];
  __shared__ float swe[6*EFEAT*NHEAD];
  __shared__ float ssum[EFEAT];
  int t = threadIdx.x;
  for (int i = t; i < L*EFEAT*NHEAD; i += 256) swe[i] = we_att[i];
  if (t < EFEAT) ssum[t] = 0.f;
  size_t p0 = (size_t)blockIdx.x*256;
  int navail = min(256, E - (int)p0);
  for (int i = t; i < navail*4; i += 256){
    uint4 v = *((const uint4*)(eap + p0*EFEAT) + i);
    int el = i >> 2, q = i & 3;
    unsigned arr[4] = {v.x, v.y, v.z, v.w};
    #pragma unroll
    for (int j = 0; j < 4; j++){
      sea[el][q*8 + j*2]     = bf2f((unsigned short)(arr[j] & 0xffff));
      sea[el][q*8 + j*2 + 1] = bf2f((unsigned short)(arr[j] >> 16));
    }
  }
  __syncthreads();
  bool ok = ((int)p0 + t < E);
  if (ok){
    float f[EFEAT];
    #pragma unroll
    for (int j = 0; j < EFEAT; j++) f[j] = sea[t][j];
    size_t p = p0 + t;
    for (int l = 0; l < L; l++){
      float a0 = 0.f, a1 = 0.f, a2 = 0.f, a3 = 0.f;
      const float* w = &swe[l*EFEAT*NHEAD];
      #pragma unroll
      for (int j = 0; j < EFEAT; j++){
        float v = f[j];
        a0 += v*w[j*4 + 0]; a1 += v*w[j*4 + 1];
        a2 += v*w[j*4 + 2]; a3 += v*w[j*4 + 3];
      }
      *(float4*)&ale[((size_t)l*E + p)*4] = make_float4(a0, a1, a2, a3);
    }
  }
  // direct LDS column sum: thread t covers col (t&31), rows [(t>>5)*32, +32)
  {
    int col = t & 31;
    int r0 = (t >> 5)*32;
    int r1 = min(r0 + 32, navail);
    float partial = 0.f;
    for (int r = r0; r < r1; r++) partial += sea[r][col];
    if (r0 < navail) atomicAdd(&ssum[col], partial);
  }
  __syncthreads();
  if (t < EFEAT) atomicAdd(&ea_sum[t], ssum[t]);
}

// ---------------- merged folds: ws_att (L*DD*8) then we_att (L*EFEAT*NHEAD) ----
__global__ __launch_bounds__(256) void fold_all_kernel(const float* __restrict__ gat_W,
    const float* __restrict__ att_src, const float* __restrict__ att_dst,
    const float* __restrict__ gat_We, const float* __restrict__ att_edge,
    float* __restrict__ ws_att, float* __restrict__ we_att, int L){
  int wave = threadIdx.x >> 6, lane = threadIdx.x & 63;
  int idx = blockIdx.x*4 + wave;
  int nWs = L*DD*8;
  if (idx < nWs){
    int j = idx & 7; int k = (idx >> 3) & 127; int l = idx >> 10;
    int h = j & 3;
    const float* att = (j < 4) ? att_src : att_dst;
    const float* av = att + (size_t)(l*NHEAD + h)*DD;
    const float* Wl = gat_W + (size_t)l*DD*HDIM + (size_t)k*HDIM + h*DD;
    float acc = Wl[lane]*av[lane] + Wl[lane + 64]*av[lane + 64];
    acc = waveReduceSum(acc);
    if (lane == 0) ws_att[idx] = acc;
  } else {
    int idx2 = idx - nWs;
    if (idx2 >= L*EFEAT*NHEAD) return;
    int h = idx2 & 3; int f = (idx2 >> 2) & 31; int l = idx2 >> 7;
    const float* av = att_edge + (size_t)(l*NHEAD + h)*DD;
    const float* Wel = gat_We + (size_t)l*EFEAT*HDIM + (size_t)f*HDIM + h*DD;
    float acc = Wel[lane]*av[lane] + Wel[lane + 64]*av[lane + 64];
    acc = waveReduceSum(acc);
    if (lane == 0) we_att[idx2] = acc;
  }
}

// ---------------- gat_W -> bf16 Bt[l][d][h*128+k], LDS-tiled transpose ----------------
__global__ __launch_bounds__(256) void bt_prep_kernel(const float* __restrict__ gat_W,
                                                      unsigned short* __restrict__ Bt, int LH){
  __shared__ float tile[32][33];
  int blk = blockIdx.x;
  int lh = blk >> 4;
  if (lh >= LH) return;
  int tl = blk & 15;
  int k0 = (tl & 3)*32, d0 = (tl >> 2)*32;
  int l = lh >> 2, h = lh & 3;
  const float* in = gat_W + (size_t)l*DD*HDIM + h*DD;
  unsigned short* outp = Bt + (size_t)l*DD*HDIM + h*DD;
  int tx = threadIdx.x & 31, ty = threadIdx.x >> 5;
  #pragma unroll
  for (int i = 0; i < 4; i++){
    int k = k0 + ty + i*8;
    tile[ty + i*8][tx] = in[(size_t)k*HDIM + d0 + tx];
  }
  __syncthreads();
  #pragma unroll
  for (int i = 0; i < 4; i++){
    int d = d0 + ty + i*8;
    outp[(size_t)d*HDIM + k0 + tx] = f2bf(tile[tx][ty + i*8]);
  }
}

// ---------------- merged small weight preps: embW^T, [W1a|W1b]^T, W1c frag ------
__global__ void wprep_kernel(const float* __restrict__ embW, const float* __restrict__ hW1,
                             unsigned short* __restrict__ Wte, unsigned short* __restrict__ Bhd,
                             unsigned short* __restrict__ Bh){
  int i = blockIdx.x*blockDim.x + threadIdx.x;
  if (i < DD*DD){
    int n = i >> 7, k = i & 127;
    Wte[i] = f2bf(embW[(size_t)k*DD + n]);
  } else if (i < DD*DD + 256*DD){
    int j = i - DD*DD;
    int n = j >> 7, k = j & 127;
    float v = (n < 128) ? hW1[(size_t)k*DD + n] : hW1[(size_t)(128 + k)*DD + (n - 128)];
    Bhd[j] = f2bf(v);
  } else if (i < DD*DD + 256*DD + 8*64*8){
    int j = i - DD*DD - 256*DD;
    int jj = j & 7, lane = (j >> 3) & 63, c = j >> 9;
    int k = (lane >> 4)*8 + jj, n = c*16 + (lane & 15);
    Bh[j] = f2bf(hW1[(size_t)2*DD*DD + (size_t)k*DD + n]);
  }
}

// ---------------- fragment-linear repacks + fold_self tail, ONE launch ----------
// Bfl[((ks*NC + c)*64 + lane)*8 + j] = Bmat[c*16 + (lane&15)][ks*32 + (lane>>4)*8 + j]
__global__ void repack_all_kernel(const unsigned short* __restrict__ Bt,
                                  const unsigned short* __restrict__ Wte,
                                  const unsigned short* __restrict__ Bhd,
                                  unsigned short* __restrict__ Btf,
                                  unsigned short* __restrict__ Wtef,
                                  unsigned short* __restrict__ Bhdf,
                                  const float* __restrict__ we_att,
                                  const float* __restrict__ ea_sum, float invE,
                                  float* __restrict__ al_self, int L){
  int idx = blockIdx.x*blockDim.x + threadIdx.x;
  constexpr int PER = DD*HDIM/8;   // 8192 uint4 per layer
  int nBt = L*PER;
  int nW  = nBt + DD*DD/8;
  int nB2 = nW + 256*DD/8;
  if (idx < nB2){
    const unsigned short* src; unsigned short* dst; int i, KD_, NC_;
    if (idx < nBt){
      int l = idx / PER; i = idx - l*PER;
      src = Bt + (size_t)l*DD*HDIM; dst = Btf + (size_t)l*DD*HDIM; KD_ = HDIM; NC_ = 8;
    } else if (idx < nW){
      i = idx - nBt; src = Wte; dst = Wtef; KD_ = DD; NC_ = 8;
    } else {
      i = idx - nW; src = Bhd; dst = Bhdf; KD_ = DD; NC_ = 16;
    }
    int lane = i & 63, rest = i >> 6;
    int c = rest % NC_, ks = rest / NC_;
    int row = c*16 + (lane & 15);
    int k0  = ks*32 + (lane >> 4)*8;
    *(uint4*)(dst + (size_t)i*8) = *(const uint4*)(src + (size_t)row*KD_ + k0);
  } else {
    int j = idx - nB2;
    if (j >= L*NHEAD) return;
    int h = j & 3; int l = j >> 2;
    float acc = 0.f;
    for (int f = 0; f < EFEAT; f++) acc += ea_sum[f]*invE * we_att[(l*EFEAT + f)*NHEAD + h];
    al_self[j] = acc;
  }
}

// ---------------- unified MFMA GEMM + fused epilogues ----------------
// 128-thread blocks (2 waves = 2-way K-split of ONE 16-row tile) with the
// software-pipelined K-loop (R13/R14-verified).
template<int KD, int NOUT>
__global__ __launch_bounds__(128, 2) void gemm_fused_kernel(
    const unsigned short* __restrict__ A, const unsigned short* __restrict__ Bfl,
    const float* __restrict__ bias, float scale, int relu, int mode,
    const float* __restrict__ ln_scale, const float* __restrict__ ln_bias,
    const float* __restrict__ gamma, const float* __restrict__ beta,
    const float* __restrict__ ws_att,
    unsigned short* __restrict__ hm_bf, float* __restrict__ al_s,
    float* __restrict__ al_d, unsigned short* __restrict__ outbf, int N){
  constexpr int NC = NOUT/16;
  constexpr int NKS = KD/64;            // ks steps per K-half
  __shared__ float s_att[8*DD];
  __shared__ float sP[4][DD];
  __shared__ f32x4 sacc[NC][64];
  int t = threadIdx.x;
  if (mode == 0){
    for (int i = t; i < DD*8; i += 128){
      int col = i & 127, j = i >> 7;
      s_att[j*DD + col] = ws_att[col*8 + j];
    }
    for (int i = t; i < DD; i += 128){
      sP[0][i] = ln_scale[i]; sP[1][i] = ln_bias[i];
      sP[2][i] = gamma[i];    sP[3][i] = beta[i];
    }
    __syncthreads();
  }
  int kh = t >> 6, lane = t & 63;
  int ln15 = lane & 15, quad = lane >> 4;
  int row0 = blockIdx.x*16;
  int arow = row0 + ln15;
  if (arow > N - 1) arow = N - 1;
  const unsigned short* aptr = A + (size_t)arow*KD + kh*(KD/2) + quad*8;
  const unsigned short* bptr = Bfl + (size_t)kh*(NKS*NC)*512 + (size_t)lane*8;

  f32x4 acc[NC];
  #pragma unroll
  for (int c = 0; c < NC; c++) acc[c] = (f32x4)(0.f);

  // ---- software-pipelined K-loop (2-stage, static double buffers) ----
  s16x8 afA, afB;
  s16x8 bA[NC], bB[NC];
  afA = *(const s16x8*)(aptr);
  #pragma unroll
  for (int c = 0; c < NC; c++)
    bA[c] = *(const s16x8*)(bptr + (size_t)c*512);
  #pragma unroll
  for (int ks = 0; ks < NKS; ks += 2){
    if (ks + 1 < NKS){
      afB = *(const s16x8*)(aptr + (ks + 1)*32);
      #pragma unroll
      for (int c = 0; c < NC; c++)
        bB[c] = *(const s16x8*)(bptr + (size_t)((ks + 1)*NC + c)*512);
    }
    #pragma unroll
    for (int c = 0; c < NC; c++)
      acc[c] = __builtin_amdgcn_mfma_f32_16x16x32_bf16(afA, bA[c], acc[c], 0, 0, 0);
    if (ks + 2 < NKS){
      afA = *(const s16x8*)(aptr + (ks + 2)*32);
      #pragma unroll
      for (int c = 0; c < NC; c++)
        bA[c] = *(const s16x8*)(bptr + (size_t)((ks + 2)*NC + c)*512);
    }
    if (ks + 1 < NKS){
      #pragma unroll
      for (int c = 0; c < NC; c++)
        acc[c] = __builtin_amdgcn_mfma_f32_16x16x32_bf16(afB, bB[c], acc[c], 0, 0, 0);
    }
  }

  if (kh){
    #pragma unroll
    for (int c = 0; c < NC; c++) sacc[c][lane] = acc[c];
  }
  __syncthreads();
  if (kh) return;
  #pragma unroll
  for (int c = 0; c < NC; c++) acc[c] += sacc[c][lane];

  float bv[NC];
  #pragma unroll
  for (int c = 0; c < NC; c++){
    if constexpr (NOUT == 256) bv[c] = (c < 8) ? bias[c*16 + ln15] : 0.f;
    else bv[c] = bias[c*16 + ln15];
  }

  #pragma unroll
  for (int r = 0; r < 4; r++){
    int row = row0 + quad*4 + r;
    bool valid = (row < N);
    float hv[NC];
    #pragma unroll
    for (int c = 0; c < NC; c++){
      float v = scale*acc[c][r] + bv[c];
      hv[c] = relu ? fmaxf(v, 0.f) : v;
    }
    if (mode == 1){
      if (valid){
        if constexpr (NOUT == 256){
          // head layout: pbuf[row][ln15*8 + c] (first 128) / [128 + ln15*8 + c-8]
          unsigned short us[16];
          #pragma unroll
          for (int c = 0; c < 16; c++) us[c] = f2bf(hv[c]);
          uint4 va, vb;
          va.x = (unsigned)us[0] | ((unsigned)us[1] << 16);
          va.y = (unsigned)us[2] | ((unsigned)us[3] << 16);
          va.z = (unsigned)us[4] | ((unsigned)us[5] << 16);
          va.w = (unsigned)us[6] | ((unsigned)us[7] << 16);
          vb.x = (unsigned)us[8] | ((unsigned)us[9] << 16);
          vb.y = (unsigned)us[10] | ((unsigned)us[11] << 16);
          vb.z = (unsigned)us[12] | ((unsigned)us[13] << 16);
          vb.w = (unsigned)us[14] | ((unsigned)us[15] << 16);
          *(uint4*)(outbf + (size_t)row*256 + ln15*8) = va;
          *(uint4*)(outbf + (size_t)row*256 + 128 + ln15*8) = vb;
        } else {
          #pragma unroll
          for (int c = 0; c < NC; c++)
            outbf[(size_t)row*NOUT + c*16 + ln15] = f2bf(hv[c]);
        }
      }
      continue;
    }
    if constexpr (NOUT == 128){
      float sum = 0.f;
      #pragma unroll
      for (int c = 0; c < NC; c++) sum += hv[c];
      sum = quadReduceSum(sum);
      float mu = sum * (1.f/128.f);
      float vs = 0.f;
      #pragma unroll
      for (int c = 0; c < NC; c++){ float d = hv[c] - mu; vs += d*d; }
      vs = quadReduceSum(vs);
      float rstd = rsqrtf(vs*(1.f/128.f) + 1e-5f);
      float m[NC];
      #pragma unroll
      for (int c = 0; c < NC; c++){
        int col = c*16 + ln15;
        float hn = (hv[c] - mu)*rstd*sP[0][col] + sP[1][col];
        m[c] = sP[2][col]*hn + sP[3][col];
        if (valid) hm_bf[(size_t)row*DD + col] = f2bf(m[c]);
      }
      float alv[8];
      #pragma unroll
      for (int j = 0; j < 8; j++){
        float a = 0.f;
        #pragma unroll
        for (int c = 0; c < NC; c++) a += m[c]*s_att[j*DD + c*16 + ln15];
        alv[j] = quadReduceSum(a);
      }
      if (ln15 == 0 && valid){
        *(float4*)&al_s[(size_t)row*4] = make_float4(alv[0], alv[1], alv[2], alv[3]);
        *(float4*)&al_d[(size_t)row*4] = make_float4(alv[4], alv[5], alv[6], alv[7]);
      }
    }
  }
}

// ---------------- fused softmax + weighted aggregation (block per node) --------
// R6-verified base; gather 8 scattered row-loads in flight.
__global__ __launch_bounds__(64) void aggregate4_kernel(
    const unsigned short* __restrict__ hm_bf, const float* __restrict__ ale,
    const float* __restrict__ al_s, const float* __restrict__ al_d,
    const float* __restrict__ al_self4, const int* __restrict__ offs,
    const int* __restrict__ csrc, unsigned short* __restrict__ z, int N){
  __shared__ float sw0[64], sw1[64], sw2[64], sw3[64];
  __shared__ int ssrc[64];
  int n = blockIdx.x, t = threadIdx.x;
  int beg = offs[n], end = offs[n + 1];
  float4 aslf = *(const float4*)al_self4;
  float4 asn = *(const float4*)&al_s[(size_t)n*4];
  float4 adn = *(const float4*)&al_d[(size_t)n*4];
  float e0 = __expf(lrelu(asn.x + adn.x + aslf.x));
  float e1 = __expf(lrelu(asn.y + adn.y + aslf.y));
  float e2 = __expf(lrelu(asn.z + adn.z + aslf.z));
  float e3 = __expf(lrelu(asn.w + adn.w + aslf.w));
  ushort2 hv = *((const ushort2*)(hm_bf + (size_t)n*DD) + t);
  float h0 = bf2f(hv.x), h1 = bf2f(hv.y);
  float ac00 = e0*h0, ac01 = e0*h1;
  float ac10 = e1*h0, ac11 = e1*h1;
  float ac20 = e2*h0, ac21 = e2*h1;
  float ac30 = e3*h0, ac31 = e3*h1;
  float den0 = e0, den1 = e1, den2 = e2, den3 = e3;
  for (int c0 = beg; c0 < end; c0 += 64){
    int p = c0 + t;
    if (p < end){
      int s = csrc[p];
      float4 ae = *(const float4*)&ale[(size_t)p*4];
      float4 as = *(const float4*)&al_s[(size_t)s*4];
      sw0[t] = __expf(lrelu(as.x + adn.x + ae.x));
      sw1[t] = __expf(lrelu(as.y + adn.y + ae.y));
      sw2[t] = __expf(lrelu(as.z + adn.z + ae.z));
      sw3[t] = __expf(lrelu(as.w + adn.w + ae.w));
      ssrc[t] = s;
    }
    __syncthreads();
    int cnt = min(64, end - c0);
    int i = 0;
    for (; i + 8 <= cnt; i += 8){   // 8-deep: keep 8 scattered row-loads in flight
      int ss[8]; ushort2 vv[8];
      #pragma unroll
      for (int k = 0; k < 8; k++) ss[k] = ssrc[i + k];
      #pragma unroll
      for (int k = 0; k < 8; k++)
        vv[k] = *((const ushort2*)(hm_bf + (size_t)ss[k]*DD) + t);
      #pragma unroll
      for (int k = 0; k < 8; k++){
        float w0 = sw0[i + k], w1 = sw1[i + k], w2 = sw2[i + k], w3 = sw3[i + k];
        float v0 = bf2f(vv[k].x), v1 = bf2f(vv[k].y);
        ac00 += w0*v0; ac01 += w0*v1;
        ac10 += w1*v0; ac11 += w1*v1;
        ac20 += w2*v0; ac21 += w2*v1;
        ac30 += w3*v0; ac31 += w3*v1;
        den0 += w0; den1 += w1; den2 += w2; den3 += w3;
      }
    }
    for (; i + 4 <= cnt; i += 4){
      int ss[4]; ushort2 vv[4];
      #pragma unroll
      for (int k = 0; k < 4; k++) ss[k] = ssrc[i + k];
      #pragma unroll
      for (int k = 0; k < 4; k++)
        vv[k] = *((const ushort2*)(hm_bf + (size_t)ss[k]*DD) + t);
      #pragma unroll
      for (int k = 0; k < 4; k++){
        float w0 = sw0[i + k], w1 = sw1[i + k], w2 = sw2[i + k], w3 = sw3[i + k];
        float v0 = bf2f(vv[k].x), v1 = bf2f(vv[k].y);
        ac00 += w0*v0; ac01 += w0*v1;
        ac10 += w1*v0; ac11 += w1*v1;
        ac20 += w2*v0; ac21 += w2*v1;
        ac30 += w3*v0; ac31 += w3*v1;
        den0 += w0; den1 += w1; den2 += w2; den3 += w3;
      }
    }
    for (; i < cnt; i++){
      int s = ssrc[i];
      float w0 = sw0[i], w1 = sw1[i], w2 = sw2[i], w3 = sw3[i];
      ushort2 v2 = *((const ushort2*)(hm_bf + (size_t)s*DD) + t);
      float v0 = bf2f(v2.x), v1 = bf2f(v2.y);
      ac00 += w0*v0; ac01 += w0*v1;
      ac10 += w1*v0; ac11 += w1*v1;
      ac20 += w2*v0; ac21 += w2*v1;
      ac30 += w3*v0; ac31 += w3*v1;
      den0 += w0; den1 += w1; den2 += w2; den3 += w3;
    }
    __syncthreads();
  }
  float r0 = 1.f/(den0 + 1e-16f), r1 = 1.f/(den1 + 1e-16f);
  float r2 = 1.f/(den2 + 1e-16f), r3 = 1.f/(den3 + 1e-16f);
  size_t zb = (size_t)n*HDIM;
  ushort2* zp = (ushort2*)(z + zb);
  zp[0*64 + t] = make_ushort2(f2bf(ac00*r0), f2bf(ac01*r0));
  zp[1*64 + t] = make_ushort2(f2bf(ac10*r1), f2bf(ac11*r1));
  zp[2*64 + t] = make_ushort2(f2bf(ac20*r2), f2bf(ac21*r2));
  zp[3*64 + t] = make_ushort2(f2bf(ac30*r3), f2bf(ac31*r3));
}

// ---------------- MFMA edge head: out[e] = relu(p[s]+p[d]+ea@W1c)@W2 + b2 ------------
__global__ __launch_bounds__(256) void head_mfma_kernel(
    const unsigned short* __restrict__ eap, const int* __restrict__ posOf,
    const unsigned short* __restrict__ Bh, const unsigned short* __restrict__ pbuf,
    const float* __restrict__ W2, const float* __restrict__ b2,
    const int* __restrict__ srcA, const int* __restrict__ dstA,
    float* __restrict__ out, int E){
  int t = threadIdx.x;
  int wave = t >> 6, lane = t & 63;
  int ln15 = lane & 15, quad = lane >> 4;
  int e0 = (blockIdx.x*4 + wave)*16;
  if (e0 >= E) return;
  int arow = e0 + ln15;
  if (arow > E - 1) arow = E - 1;
  int ap = posOf[arow];
  s16x8 a = *(const s16x8*)(eap + (size_t)ap*EFEAT + quad*8);
  // hoist scattered pbuf loads for all 4 output rows
  int sArr[4], dArr[4];
  #pragma unroll
  for (int r = 0; r < 4; r++){
    int e = e0 + quad*4 + r;
    int ec = (e < E) ? e : E - 1;
    sArr[r] = srcA[ec]; dArr[r] = dstA[ec];
  }
  s16x8 pa[4], pb[4];
  #pragma unroll
  for (int r = 0; r < 4; r++){
    pa[r] = *(const s16x8*)(pbuf + (size_t)sArr[r]*256 + ln15*8);
    pb[r] = *(const s16x8*)(pbuf + (size_t)dArr[r]*256 + 128 + ln15*8);
  }
  f32x4 acc[8];
  #pragma unroll
  for (int c = 0; c < 8; c++){
    s16x8 b = *(const s16x8*)(Bh + ((size_t)c*64 + lane)*8);
    acc[c] = __builtin_amdgcn_mfma_f32_16x16x32_bf16(a, b, (f32x4)(0.f), 0, 0, 0);
  }
  float w2v[8];
  #pragma unroll
  for (int c = 0; c < 8; c++) w2v[c] = W2[c*16 + ln15];
  float res[4];
  #pragma unroll
  for (int r = 0; r < 4; r++){
    float sum = 0.f;
    #pragma unroll
    for (int c = 0; c < 8; c++){
      float q = acc[c][r] + bf2f((unsigned short)pa[r][c]) + bf2f((unsigned short)pb[r][c]);
      sum += fmaxf(q, 0.f) * w2v[c];
    }
    res[r] = sum;
  }
  #pragma unroll
  for (int r = 0; r < 4; r++){
    float v = res[r];
    v += __shfl_xor(v, 1, 64); v += __shfl_xor(v, 2, 64);
    v += __shfl_xor(v, 4, 64); v += __shfl_xor(v, 8, 64);
    res[r] = v;
  }
  if (ln15 == 0){
    float bb = b2[0];
    #pragma unroll
    for (int r = 0; r < 4; r++){
      int e = e0 + quad*4 + r;
      if (e < E) out[e] = res[r] + bb;
    }
  }
}

extern "C" void kernel_launch(void* const* d_in, const int* in_sizes, int n_in,
                              void* d_out, int out_size, void* d_ws, size_t ws_size,
                              hipStream_t stream){
  const float* x      = (const float*)d_in[0];
  const int*   eidx   = (const int*)d_in[1];
  const float* eattr  = (const float*)d_in[2];
  const float* gamma  = (const float*)d_in[3];
  const float* beta   = (const float*)d_in[4];
  const float* embW   = (const float*)d_in[5];
  const float* embB   = (const float*)d_in[6];
  const float* lnS    = (const float*)d_in[7];
  const float* lnB    = (const float*)d_in[8];
  const float* gatW   = (const float*)d_in[9];
  const float* attS   = (const float*)d_in[10];
  const float* attD   = (const float*)d_in[11];
  const float* gatWe  = (const float*)d_in[12];
  const float* attE   = (const float*)d_in[13];
  const float* gatB   = (const float*)d_in[14];
  const float* hW1    = (const float*)d_in[15];
  const float* hB1    = (const float*)d_in[16];
  const float* hW2    = (const float*)d_in[17];
  const float* hB2    = (const float*)d_in[18];
  float* out = (float*)d_out;

  int N = in_sizes[0] / DD;
  int E = in_sizes[1] / 2;
  int L = in_sizes[3] / DD;
  int Npad = (N + 63) & ~63;

  const int* srcA = eidx;
  const int* dstA = eidx + E;

  float* ws = (float*)d_ws;
  float* ea_sum  = ws + 0;
  float* we_att  = ws + 64;
  float* al_self = ws + 1024;
  float* ws_att  = ws + 2048;
  size_t o = 8192;
  int* deg    = (int*)(ws + o); o += N;
  int* offs   = (int*)(ws + o); o += N + 1;
  int* cursor = (int*)(ws + o); o += N;
  int* csrc   = (int*)(ws + o); o += E;
  int* posOf  = (int*)(ws + o); o += E;
  o = (o + 255) & ~(size_t)255;
  unsigned short* Bt  = (unsigned short*)(ws + o); o += (size_t)L*DD*HDIM/2;
  unsigned short* Btf = (unsigned short*)(ws + o); o += (size_t)L*DD*HDIM/2;
  unsigned short* Bh  = (unsigned short*)(ws + o); o += 8*64*8/2;
  unsigned short* Wte = (unsigned short*)(ws + o); o += DD*DD/2;
  unsigned short* Wtef= (unsigned short*)(ws + o); o += DD*DD/2;
  unsigned short* Bhd = (unsigned short*)(ws + o); o += 256*DD/2;
  unsigned short* Bhdf= (unsigned short*)(ws + o); o += 256*DD/2;
  unsigned short* xbf = (unsigned short*)(ws + o); o += (size_t)N*DD/2;
  unsigned short* hm_bf = (unsigned short*)(ws + o); o += (size_t)N*DD/2;
  float* al_s  = ws + o; o += (size_t)N*4;
  float* al_d  = ws + o; o += (size_t)N*4;
  unsigned short* eap = (unsigned short*)(ws + o); o += (size_t)E*EFEAT/2;
  float* ale   = ws + o; o += (size_t)L*E*4;
  unsigned short* z = (unsigned short*)(ws + o); o += (size_t)Npad*HDIM/2;
  unsigned short* hbf  = hm_bf;
  unsigned short* pbuf = z;

  hipMemsetAsync(ea_sum, 0, EFEAT*sizeof(float), stream);
  hipMemsetAsync(deg, 0, (size_t)N*sizeof(int), stream);
  hist_kernel<<<(E + 255)/256, 256, 0, stream>>>(dstA, deg, E);
  scan_kernel<<<1, 1024, 0, stream>>>(deg, offs, cursor, N);
  scatter_kernel<<<(E + 255)/256, 256, 0, stream>>>(dstA, srcA, cursor, csrc, posOf, E);
  eap_bf16_kernel<<<(E*8 + N*DD/4 + 255)/256, 256, 0, stream>>>(
      eattr, posOf, eap, x, xbf, E, N*DD/4);
  fold_all_kernel<<<(L*DD*8 + L*EFEAT*NHEAD + 3)/4, 256, 0, stream>>>(
      gatW, attS, attD, gatWe, attE, ws_att, we_att, L);
  bt_prep_kernel<<<L*NHEAD*16, 256, 0, stream>>>(gatW, Bt, L*NHEAD);
  wprep_kernel<<<(DD*DD + 256*DD + 8*64*8 + 255)/256, 256, 0, stream>>>(
      embW, hW1, Wte, Bhd, Bh);
  ale_prep_kernel<<<(E + 255)/256, 256, 0, stream>>>(eap, we_att, ale, ea_sum, E, L);
  repack_all_kernel<<<(L*DD*HDIM/8 + DD*DD/8 + 256*DD/8 + L*NHEAD + 255)/256, 256, 0, stream>>>(
      Bt, Wte, Bhd, Btf, Wtef, Bhdf, we_att, ea_sum, 1.0f/(float)E, al_self, L);

  // embed + LN/FiLM/al (layer 0)
  gemm_fused_kernel<128,128><<<(N + 15)/16, 128, 0, stream>>>(
      xbf, Wtef, embB, 1.0f, 0, 0, lnS, lnB, gamma, beta, ws_att,
      hm_bf, al_s, al_d, nullptr, N);

  for (int l = 0; l < L; l++){
    aggregate4_kernel<<<N, 64, 0, stream>>>(hm_bf, ale + (size_t)l*E*4,
        al_s, al_d, al_self + (size_t)l*NHEAD, offs, csrc, z, N);
    if (l < L - 1){
      gemm_fused_kernel<512,128><<<(N + 15)/16, 128, 0, stream>>>(
          z, Btf + (size_t)l*DD*HDIM, gatB + (size_t)l*DD, 0.25f, 1, 0,
          lnS + (l+1)*DD, lnB + (l+1)*DD, gamma + (l+1)*DD, beta + (l+1)*DD,
          ws_att + (size_t)(l+1)*DD*8, hm_bf, al_s, al_d, nullptr, N);
    } else {
      gemm_fused_kernel<512,128><<<(N + 15)/16, 128, 0, stream>>>(
          z, Btf + (size_t)l*DD*HDIM, gatB + (size_t)l*DD, 0.25f, 1, 1,
          nullptr, nullptr, nullptr, nullptr, nullptr,
          nullptr, nullptr, nullptr, hbf, N);
    }
  }

  // head pre-projection: pbuf[N,256] = hbf @ [W1a|W1b] (+hB1 on cols<128)
  gemm_fused_kernel<128,256><<<(N + 15)/16, 128, 0, stream>>>(
      hbf, Bhdf, hB1, 1.0f, 0, 1, nullptr, nullptr, nullptr, nullptr, nullptr,
      nullptr, nullptr, nullptr, pbuf, N);

  head_mfma_kernel<<<(E + 63)/64, 256, 0, stream>>>(eap, posOf, Bh, pbuf,
      hW2, hB2, srcA, dstA, out, E);
}

// Round 16
// 574.789 us; speedup vs baseline: 1.0604x; 1.0604x over previous
//
#include <hip/hip_runtime.h>

#define DD 128      // GNN_DIM == NODE_FEAT
#define HDIM 512    // H * D
#define EFEAT 32
#define NHEAD 4
#define SCHUNK 2048

typedef short s16x8 __attribute__((ext_vector_type(8)));
typedef float f32x4 __attribute__((ext_vector_type(4)));

__device__ __forceinline__ float lrelu(float x){ return x > 0.f ? x : 0.2f*x; }

__device__ __forceinline__ unsigned short f2bf(float f){
  unsigned u = __float_as_uint(f);
  unsigned r = (u + 0x7FFFu + ((u >> 16) & 1u)) >> 16;
  return (unsigned short)r;
}
__device__ __forceinline__ float bf2f(unsigned short u){
  return __uint_as_float(((unsigned)u) << 16);
}

__device__ __forceinline__ float waveReduceSum(float v){
  #pragma unroll
  for (int m = 1; m < 64; m <<= 1) v += __shfl_xor(v, m, 64);
  return v;
}
__device__ __forceinline__ int waveReduceSumI(int v){
  #pragma unroll
  for (int m = 1; m < 64; m <<= 1) v += __shfl_xor(v, m, 64);
  return v;
}
__device__ __forceinline__ float quadReduceSum(float v){
  v += __shfl_xor(v, 1, 64); v += __shfl_xor(v, 2, 64);
  v += __shfl_xor(v, 4, 64); v += __shfl_xor(v, 8, 64);
  return v;
}

// ---------------- CSR build over dst ----------------
__global__ void hist_kernel(const int* __restrict__ dst, int* __restrict__ deg, int E){
  int e = blockIdx.x*blockDim.x + threadIdx.x;
  if (e < E) atomicAdd(&deg[dst[e]], 1);
}

// ---- 3-phase parallel scan (replaces the 47us single-block scan) ----
__global__ void scan_part_kernel(const int* __restrict__ deg, int* __restrict__ bsum, int N){
  __shared__ int s[4];
  int b = blockIdx.x, t = threadIdx.x;
  int base = b*SCHUNK;
  int hi = min(base + SCHUNK, N);
  int sum = 0;
  for (int i = base + t; i < hi; i += 256) sum += deg[i];
  sum = waveReduceSumI(sum);
  if ((t & 63) == 0) s[t >> 6] = sum;
  __syncthreads();
  if (t == 0) bsum[b] = s[0] + s[1] + s[2] + s[3];
}

__global__ void scan_top_kernel(const int* __restrict__ bsum, int* __restrict__ boff,
                                int* __restrict__ offs, int N, int nb){
  if (threadIdx.x == 0){
    int run = 0;
    for (int i = 0; i < nb; i++){ boff[i] = run; run += bsum[i]; }
    offs[N] = run;
  }
}

__global__ void scan_fin_kernel(const int* __restrict__ deg, const int* __restrict__ boff,
                                int* __restrict__ offs, int* __restrict__ cursor, int N){
  __shared__ int s[256];
  int b = blockIdx.x, t = threadIdx.x;
  int i0 = b*SCHUNK + t*8;
  int vals[8];
  int lsum = 0;
  #pragma unroll
  for (int k = 0; k < 8; k++){
    int i = i0 + k;
    vals[k] = (i < N) ? deg[i] : 0;
    lsum += vals[k];
  }
  s[t] = lsum;
  __syncthreads();
  for (int d = 1; d < 256; d <<= 1){
    int x = (t >= d) ? s[t - d] : 0;
    __syncthreads();
    s[t] += x;
    __syncthreads();
  }
  int run = boff[b] + s[t] - lsum;
  #pragma unroll
  for (int k = 0; k < 8; k++){
    int i = i0 + k;
    if (i < N){ offs[i] = run; cursor[i] = run; run += vals[k]; }
  }
}

__global__ void scatter_kernel(const int* __restrict__ dst, const int* __restrict__ src,
                               int* __restrict__ cursor, int* __restrict__ csrc,
                               int* __restrict__ posOf, int E){
  int e = blockIdx.x*blockDim.x + threadIdx.x;
  if (e < E){
    int d = dst[e];
    int p = atomicAdd(&cursor[d], 1);
    csrc[p] = src[e];
    posOf[e] = p;
  }
}

// ---------------- merged: edge attrs -> bf16 CSR scatter  +  x -> bf16 ---------
__global__ void eap_bf16_kernel(const float* __restrict__ ea, const int* __restrict__ posOf,
                                unsigned short* __restrict__ eap,
                                const float* __restrict__ x, unsigned short* __restrict__ xbf,
                                int E, int nvec){
  int idx = blockIdx.x*blockDim.x + threadIdx.x;
  int nEap = E*8;
  if (idx < nEap){
    int e = idx >> 3, q = idx & 7;
    int p = posOf[e];
    float4 v = *((const float4*)(ea + (size_t)e*EFEAT) + q);
    ushort4 u = make_ushort4(f2bf(v.x), f2bf(v.y), f2bf(v.z), f2bf(v.w));
    *((ushort4*)(eap + (size_t)p*EFEAT) + q) = u;
  } else {
    int i = idx - nEap;
    if (i >= nvec) return;
    float4 v = *((const float4*)x + i);
    *((ushort4*)xbf + i) = make_ushort4(f2bf(v.x), f2bf(v.y), f2bf(v.z), f2bf(v.w));
  }
}

// ---------------- per-edge attention logits for ALL layers + ea column sums ----
__global__ __launch_bounds__(256) void ale_prep_kernel(
    const unsigned short* __restrict__ eap, const float* __restrict__ we_att,
    float* __restrict__ ale, float* __restrict__ ea_sum, int E, int L){
  __shared__ float sea[256][33];
  __shared__ float swe[6*EFEAT*NHEAD];
  __shared__ float ssum[EFEAT];
  int t = threadIdx.x;
  for (int i = t; i < L*EFEAT*NHEAD; i += 256) swe[i] = we_att[i];
  if (t < EFEAT) ssum[t] = 0.f;
  size_t p0 = (size_t)blockIdx.x*256;
  int navail = min(256, E - (int)p0);
  for (int i = t; i < navail*4; i += 256){
    uint4 v = *((const uint4*)(eap + p0*EFEAT) + i);
    int el = i >> 2, q = i & 3;
    unsigned arr[4] = {v.x, v.y, v.z, v.w};
    #pragma unroll
    for (int j = 0; j < 4; j++){
      sea[el][q*8 + j*2]     = bf2f((unsigned short)(arr[j] & 0xffff));
      sea[el][q*8 + j*2 + 1] = bf2f((unsigned short)(arr[j] >> 16));
    }
  }
  __syncthreads();
  bool ok = ((int)p0 + t < E);
  if (ok){
    float f[EFEAT];
    #pragma unroll
    for (int j = 0; j < EFEAT; j++) f[j] = sea[t][j];
    size_t p = p0 + t;
    for (int l = 0; l < L; l++){
      float a0 = 0.f, a1 = 0.f, a2 = 0.f, a3 = 0.f;
      const float* w = &swe[l*EFEAT*NHEAD];
      #pragma unroll
      for (int j = 0; j < EFEAT; j++){
        float v = f[j];
        a0 += v*w[j*4 + 0]; a1 += v*w[j*4 + 1];
        a2 += v*w[j*4 + 2]; a3 += v*w[j*4 + 3];
      }
      *(float4*)&ale[((size_t)l*E + p)*4] = make_float4(a0, a1, a2, a3);
    }
  }
  // direct LDS column sum: thread t covers col (t&31), rows [(t>>5)*32, +32)
  {
    int col = t & 31;
    int r0 = (t >> 5)*32;
    int r1 = min(r0 + 32, navail);
    float partial = 0.f;
    for (int r = r0; r < r1; r++) partial += sea[r][col];
    if (r0 < navail) atomicAdd(&ssum[col], partial);
  }
  __syncthreads();
  if (t < EFEAT) atomicAdd(&ea_sum[t], ssum[t]);
}

// ---------------- merged folds: ws_att (L*DD*8) then we_att (L*EFEAT*NHEAD) ----
__global__ __launch_bounds__(256) void fold_all_kernel(const float* __restrict__ gat_W,
    const float* __restrict__ att_src, const float* __restrict__ att_dst,
    const float* __restrict__ gat_We, const float* __restrict__ att_edge,
    float* __restrict__ ws_att, float* __restrict__ we_att, int L){
  int wave = threadIdx.x >> 6, lane = threadIdx.x & 63;
  int idx = blockIdx.x*4 + wave;
  int nWs = L*DD*8;
  if (idx < nWs){
    int j = idx & 7; int k = (idx >> 3) & 127; int l = idx >> 10;
    int h = j & 3;
    const float* att = (j < 4) ? att_src : att_dst;
    const float* av = att + (size_t)(l*NHEAD + h)*DD;
    const float* Wl = gat_W + (size_t)l*DD*HDIM + (size_t)k*HDIM + h*DD;
    float acc = Wl[lane]*av[lane] + Wl[lane + 64]*av[lane + 64];
    acc = waveReduceSum(acc);
    if (lane == 0) ws_att[idx] = acc;
  } else {
    int idx2 = idx - nWs;
    if (idx2 >= L*EFEAT*NHEAD) return;
    int h = idx2 & 3; int f = (idx2 >> 2) & 31; int l = idx2 >> 7;
    const float* av = att_edge + (size_t)(l*NHEAD + h)*DD;
    const float* Wel = gat_We + (size_t)l*EFEAT*HDIM + (size_t)f*HDIM + h*DD;
    float acc = Wel[lane]*av[lane] + Wel[lane + 64]*av[lane + 64];
    acc = waveReduceSum(acc);
    if (lane == 0) we_att[idx2] = acc;
  }
}

// ---------------- gat_W -> bf16 Bt[l][d][h*128+k], LDS-tiled transpose ----------------
__global__ __launch_bounds__(256) void bt_prep_kernel(const float* __restrict__ gat_W,
                                                      unsigned short* __restrict__ Bt, int LH){
  __shared__ float tile[32][33];
  int blk = blockIdx.x;
  int lh = blk >> 4;
  if (lh >= LH) return;
  int tl = blk & 15;
  int k0 = (tl & 3)*32, d0 = (tl >> 2)*32;
  int l = lh >> 2, h = lh & 3;
  const float* in = gat_W + (size_t)l*DD*HDIM + h*DD;
  unsigned short* outp = Bt + (size_t)l*DD*HDIM + h*DD;
  int tx = threadIdx.x & 31, ty = threadIdx.x >> 5;
  #pragma unroll
  for (int i = 0; i < 4; i++){
    int k = k0 + ty + i*8;
    tile[ty + i*8][tx] = in[(size_t)k*HDIM + d0 + tx];
  }
  __syncthreads();
  #pragma unroll
  for (int i = 0; i < 4; i++){
    int d = d0 + ty + i*8;
    outp[(size_t)d*HDIM + k0 + tx] = f2bf(tile[tx][ty + i*8]);
  }
}

// ---------------- merged small weight preps: embW^T, [W1a|W1b]^T, W1c frag ------
__global__ void wprep_kernel(const float* __restrict__ embW, const float* __restrict__ hW1,
                             unsigned short* __restrict__ Wte, unsigned short* __restrict__ Bhd,
                             unsigned short* __restrict__ Bh){
  int i = blockIdx.x*blockDim.x + threadIdx.x;
  if (i < DD*DD){
    int n = i >> 7, k = i & 127;
    Wte[i] = f2bf(embW[(size_t)k*DD + n]);
  } else if (i < DD*DD + 256*DD){
    int j = i - DD*DD;
    int n = j >> 7, k = j & 127;
    float v = (n < 128) ? hW1[(size_t)k*DD + n] : hW1[(size_t)(128 + k)*DD + (n - 128)];
    Bhd[j] = f2bf(v);
  } else if (i < DD*DD + 256*DD + 8*64*8){
    int j = i - DD*DD - 256*DD;
    int jj = j & 7, lane = (j >> 3) & 63, c = j >> 9;
    int k = (lane >> 4)*8 + jj, n = c*16 + (lane & 15);
    Bh[j] = f2bf(hW1[(size_t)2*DD*DD + (size_t)k*DD + n]);
  }
}

// ---------------- fragment-linear repacks + fold_self tail, ONE launch ----------
__global__ void repack_all_kernel(const unsigned short* __restrict__ Bt,
                                  const unsigned short* __restrict__ Wte,
                                  const unsigned short* __restrict__ Bhd,
                                  unsigned short* __restrict__ Btf,
                                  unsigned short* __restrict__ Wtef,
                                  unsigned short* __restrict__ Bhdf,
                                  const float* __restrict__ we_att,
                                  const float* __restrict__ ea_sum, float invE,
                                  float* __restrict__ al_self, int L){
  int idx = blockIdx.x*blockDim.x + threadIdx.x;
  constexpr int PER = DD*HDIM/8;   // 8192 uint4 per layer
  int nBt = L*PER;
  int nW  = nBt + DD*DD/8;
  int nB2 = nW + 256*DD/8;
  if (idx < nB2){
    const unsigned short* src; unsigned short* dst; int i, KD_, NC_;
    if (idx < nBt){
      int l = idx / PER; i = idx - l*PER;
      src = Bt + (size_t)l*DD*HDIM; dst = Btf + (size_t)l*DD*HDIM; KD_ = HDIM; NC_ = 8;
    } else if (idx < nW){
      i = idx - nBt; src = Wte; dst = Wtef; KD_ = DD; NC_ = 8;
    } else {
      i = idx - nW; src = Bhd; dst = Bhdf; KD_ = DD; NC_ = 16;
    }
    int lane = i & 63, rest = i >> 6;
    int c = rest % NC_, ks = rest / NC_;
    int row = c*16 + (lane & 15);
    int k0  = ks*32 + (lane >> 4)*8;
    *(uint4*)(dst + (size_t)i*8) = *(const uint4*)(src + (size_t)row*KD_ + k0);
  } else {
    int j = idx - nB2;
    if (j >= L*NHEAD) return;
    int h = j & 3; int l = j >> 2;
    float acc = 0.f;
    for (int f = 0; f < EFEAT; f++) acc += ea_sum[f]*invE * we_att[(l*EFEAT + f)*NHEAD + h];
    al_self[j] = acc;
  }
}

// ---------------- unified MFMA GEMM + fused epilogues ----------------
// 128-thread blocks (2 waves = 2-way K-split of ONE 16-row tile) with the
// software-pipelined K-loop (R13/R14-verified).
template<int KD, int NOUT>
__global__ __launch_bounds__(128, 2) void gemm_fused_kernel(
    const unsigned short* __restrict__ A, const unsigned short* __restrict__ Bfl,
    const float* __restrict__ bias, float scale, int relu, int mode,
    const float* __restrict__ ln_scale, const float* __restrict__ ln_bias,
    const float* __restrict__ gamma, const float* __restrict__ beta,
    const float* __restrict__ ws_att,
    unsigned short* __restrict__ hm_bf, float* __restrict__ al_s,
    float* __restrict__ al_d, unsigned short* __restrict__ outbf, int N){
  constexpr int NC = NOUT/16;
  constexpr int NKS = KD/64;            // ks steps per K-half
  __shared__ float s_att[8*DD];
  __shared__ float sP[4][DD];
  __shared__ f32x4 sacc[NC][64];
  int t = threadIdx.x;
  if (mode == 0){
    for (int i = t; i < DD*8; i += 128){
      int col = i & 127, j = i >> 7;
      s_att[j*DD + col] = ws_att[col*8 + j];
    }
    for (int i = t; i < DD; i += 128){
      sP[0][i] = ln_scale[i]; sP[1][i] = ln_bias[i];
      sP[2][i] = gamma[i];    sP[3][i] = beta[i];
    }
    __syncthreads();
  }
  int kh = t >> 6, lane = t & 63;
  int ln15 = lane & 15, quad = lane >> 4;
  int row0 = blockIdx.x*16;
  int arow = row0 + ln15;
  if (arow > N - 1) arow = N - 1;
  const unsigned short* aptr = A + (size_t)arow*KD + kh*(KD/2) + quad*8;
  const unsigned short* bptr = Bfl + (size_t)kh*(NKS*NC)*512 + (size_t)lane*8;

  f32x4 acc[NC];
  #pragma unroll
  for (int c = 0; c < NC; c++) acc[c] = (f32x4)(0.f);

  // ---- software-pipelined K-loop (2-stage, static double buffers) ----
  s16x8 afA, afB;
  s16x8 bA[NC], bB[NC];
  afA = *(const s16x8*)(aptr);
  #pragma unroll
  for (int c = 0; c < NC; c++)
    bA[c] = *(const s16x8*)(bptr + (size_t)c*512);
  #pragma unroll
  for (int ks = 0; ks < NKS; ks += 2){
    if (ks + 1 < NKS){
      afB = *(const s16x8*)(aptr + (ks + 1)*32);
      #pragma unroll
      for (int c = 0; c < NC; c++)
        bB[c] = *(const s16x8*)(bptr + (size_t)((ks + 1)*NC + c)*512);
    }
    #pragma unroll
    for (int c = 0; c < NC; c++)
      acc[c] = __builtin_amdgcn_mfma_f32_16x16x32_bf16(afA, bA[c], acc[c], 0, 0, 0);
    if (ks + 2 < NKS){
      afA = *(const s16x8*)(aptr + (ks + 2)*32);
      #pragma unroll
      for (int c = 0; c < NC; c++)
        bA[c] = *(const s16x8*)(bptr + (size_t)((ks + 2)*NC + c)*512);
    }
    if (ks + 1 < NKS){
      #pragma unroll
      for (int c = 0; c < NC; c++)
        acc[c] = __builtin_amdgcn_mfma_f32_16x16x32_bf16(afB, bB[c], acc[c], 0, 0, 0);
    }
  }

  if (kh){
    #pragma unroll
    for (int c = 0; c < NC; c++) sacc[c][lane] = acc[c];
  }
  __syncthreads();
  if (kh) return;
  #pragma unroll
  for (int c = 0; c < NC; c++) acc[c] += sacc[c][lane];

  float bv[NC];
  #pragma unroll
  for (int c = 0; c < NC; c++){
    if constexpr (NOUT == 256) bv[c] = (c < 8) ? bias[c*16 + ln15] : 0.f;
    else bv[c] = bias[c*16 + ln15];
  }

  #pragma unroll
  for (int r = 0; r < 4; r++){
    int row = row0 + quad*4 + r;
    bool valid = (row < N);
    float hv[NC];
    #pragma unroll
    for (int c = 0; c < NC; c++){
      float v = scale*acc[c][r] + bv[c];
      hv[c] = relu ? fmaxf(v, 0.f) : v;
    }
    if (mode == 1){
      if (valid){
        if constexpr (NOUT == 256){
          // head layout: pbuf[row][ln15*8 + c] (first 128) / [128 + ln15*8 + c-8]
          unsigned short us[16];
          #pragma unroll
          for (int c = 0; c < 16; c++) us[c] = f2bf(hv[c]);
          uint4 va, vb;
          va.x = (unsigned)us[0] | ((unsigned)us[1] << 16);
          va.y = (unsigned)us[2] | ((unsigned)us[3] << 16);
          va.z = (unsigned)us[4] | ((unsigned)us[5] << 16);
          va.w = (unsigned)us[6] | ((unsigned)us[7] << 16);
          vb.x = (unsigned)us[8] | ((unsigned)us[9] << 16);
          vb.y = (unsigned)us[10] | ((unsigned)us[11] << 16);
          vb.z = (unsigned)us[12] | ((unsigned)us[13] << 16);
          vb.w = (unsigned)us[14] | ((unsigned)us[15] << 16);
          *(uint4*)(outbf + (size_t)row*256 + ln15*8) = va;
          *(uint4*)(outbf + (size_t)row*256 + 128 + ln15*8) = vb;
        } else {
          #pragma unroll
          for (int c = 0; c < NC; c++)
            outbf[(size_t)row*NOUT + c*16 + ln15] = f2bf(hv[c]);
        }
      }
      continue;
    }
    if constexpr (NOUT == 128){
      float sum = 0.f;
      #pragma unroll
      for (int c = 0; c < NC; c++) sum += hv[c];
      sum = quadReduceSum(sum);
      float mu = sum * (1.f/128.f);
      float vs = 0.f;
      #pragma unroll
      for (int c = 0; c < NC; c++){ float d = hv[c] - mu; vs += d*d; }
      vs = quadReduceSum(vs);
      float rstd = rsqrtf(vs*(1.f/128.f) + 1e-5f);
      float m[NC];
      #pragma unroll
      for (int c = 0; c < NC; c++){
        int col = c*16 + ln15;
        float hn = (hv[c] - mu)*rstd*sP[0][col] + sP[1][col];
        m[c] = sP[2][col]*hn + sP[3][col];
        if (valid) hm_bf[(size_t)row*DD + col] = f2bf(m[c]);
      }
      float alv[8];
      #pragma unroll
      for (int j = 0; j < 8; j++){
        float a = 0.f;
        #pragma unroll
        for (int c = 0; c < NC; c++) a += m[c]*s_att[j*DD + c*16 + ln15];
        alv[j] = quadReduceSum(a);
      }
      if (ln15 == 0 && valid){
        *(float4*)&al_s[(size_t)row*4] = make_float4(alv[0], alv[1], alv[2], alv[3]);
        *(float4*)&al_d[(size_t)row*4] = make_float4(alv[4], alv[5], alv[6], alv[7]);
      }
    }
  }
}

// ---------------- fused softmax + weighted aggregation (block per node) --------
__global__ __launch_bounds__(64) void aggregate4_kernel(
    const unsigned short* __restrict__ hm_bf, const float* __restrict__ ale,
    const float* __restrict__ al_s, const float* __restrict__ al_d,
    const float* __restrict__ al_self4, const int* __restrict__ offs,
    const int* __restrict__ csrc, unsigned short* __restrict__ z, int N){
  __shared__ float sw0[64], sw1[64], sw2[64], sw3[64];
  __shared__ int ssrc[64];
  int n = blockIdx.x, t = threadIdx.x;
  int beg = offs[n], end = offs[n + 1];
  float4 aslf = *(const float4*)al_self4;
  float4 asn = *(const float4*)&al_s[(size_t)n*4];
  float4 adn = *(const float4*)&al_d[(size_t)n*4];
  float e0 = __expf(lrelu(asn.x + adn.x + aslf.x));
  float e1 = __expf(lrelu(asn.y + adn.y + aslf.y));
  float e2 = __expf(lrelu(asn.z + adn.z + aslf.z));
  float e3 = __expf(lrelu(asn.w + adn.w + aslf.w));
  ushort2 hv = *((const ushort2*)(hm_bf + (size_t)n*DD) + t);
  float h0 = bf2f(hv.x), h1 = bf2f(hv.y);
  float ac00 = e0*h0, ac01 = e0*h1;
  float ac10 = e1*h0, ac11 = e1*h1;
  float ac20 = e2*h0, ac21 = e2*h1;
  float ac30 = e3*h0, ac31 = e3*h1;
  float den0 = e0, den1 = e1, den2 = e2, den3 = e3;
  for (int c0 = beg; c0 < end; c0 += 64){
    int p = c0 + t;
    if (p < end){
      int s = csrc[p];
      float4 ae = *(const float4*)&ale[(size_t)p*4];
      float4 as = *(const float4*)&al_s[(size_t)s*4];
      sw0[t] = __expf(lrelu(as.x + adn.x + ae.x));
      sw1[t] = __expf(lrelu(as.y + adn.y + ae.y));
      sw2[t] = __expf(lrelu(as.z + adn.z + ae.z));
      sw3[t] = __expf(lrelu(as.w + adn.w + ae.w));
      ssrc[t] = s;
    }
    __syncthreads();
    int cnt = min(64, end - c0);
    int i = 0;
    for (; i + 8 <= cnt; i += 8){   // 8-deep: keep 8 scattered row-loads in flight
      int ss[8]; ushort2 vv[8];
      #pragma unroll
      for (int k = 0; k < 8; k++) ss[k] = ssrc[i + k];
      #pragma unroll
      for (int k = 0; k < 8; k++)
        vv[k] = *((const ushort2*)(hm_bf + (size_t)ss[k]*DD) + t);
      #pragma unroll
      for (int k = 0; k < 8; k++){
        float w0 = sw0[i + k], w1 = sw1[i + k], w2 = sw2[i + k], w3 = sw3[i + k];
        float v0 = bf2f(vv[k].x), v1 = bf2f(vv[k].y);
        ac00 += w0*v0; ac01 += w0*v1;
        ac10 += w1*v0; ac11 += w1*v1;
        ac20 += w2*v0; ac21 += w2*v1;
        ac30 += w3*v0; ac31 += w3*v1;
        den0 += w0; den1 += w1; den2 += w2; den3 += w3;
      }
    }
    for (; i + 4 <= cnt; i += 4){
      int ss[4]; ushort2 vv[4];
      #pragma unroll
      for (int k = 0; k < 4; k++) ss[k] = ssrc[i + k];
      #pragma unroll
      for (int k = 0; k < 4; k++)
        vv[k] = *((const ushort2*)(hm_bf + (size_t)ss[k]*DD) + t);
      #pragma unroll
      for (int k = 0; k < 4; k++){
        float w0 = sw0[i + k], w1 = sw1[i + k], w2 = sw2[i + k], w3 = sw3[i + k];
        float v0 = bf2f(vv[k].x), v1 = bf2f(vv[k].y);
        ac00 += w0*v0; ac01 += w0*v1;
        ac10 += w1*v0; ac11 += w1*v1;
        ac20 += w2*v0; ac21 += w2*v1;
        ac30 += w3*v0; ac31 += w3*v1;
        den0 += w0; den1 += w1; den2 += w2; den3 += w3;
      }
    }
    for (; i < cnt; i++){
      int s = ssrc[i];
      float w0 = sw0[i], w1 = sw1[i], w2 = sw2[i], w3 = sw3[i];
      ushort2 v2 = *((const ushort2*)(hm_bf + (size_t)s*DD) + t);
      float v0 = bf2f(v2.x), v1 = bf2f(v2.y);
      ac00 += w0*v0; ac01 += w0*v1;
      ac10 += w1*v0; ac11 += w1*v1;
      ac20 += w2*v0; ac21 += w2*v1;
      ac30 += w3*v0; ac31 += w3*v1;
      den0 += w0; den1 += w1; den2 += w2; den3 += w3;
    }
    __syncthreads();
  }
  float r0 = 1.f/(den0 + 1e-16f), r1 = 1.f/(den1 + 1e-16f);
  float r2 = 1.f/(den2 + 1e-16f), r3 = 1.f/(den3 + 1e-16f);
  size_t zb = (size_t)n*HDIM;
  ushort2* zp = (ushort2*)(z + zb);
  zp[0*64 + t] = make_ushort2(f2bf(ac00*r0), f2bf(ac01*r0));
  zp[1*64 + t] = make_ushort2(f2bf(ac10*r1), f2bf(ac11*r1));
  zp[2*64 + t] = make_ushort2(f2bf(ac20*r2), f2bf(ac21*r2));
  zp[3*64 + t] = make_ushort2(f2bf(ac30*r3), f2bf(ac31*r3));
}

// ---------------- MFMA edge head: out[e] = relu(p[s]+p[d]+ea@W1c)@W2 + b2 ------------
__global__ __launch_bounds__(256) void head_mfma_kernel(
    const unsigned short* __restrict__ eap, const int* __restrict__ posOf,
    const unsigned short* __restrict__ Bh, const unsigned short* __restrict__ pbuf,
    const float* __restrict__ W2, const float* __restrict__ b2,
    const int* __restrict__ srcA, const int* __restrict__ dstA,
    float* __restrict__ out, int E){
  int t = threadIdx.x;
  int wave = t >> 6, lane = t & 63;
  int ln15 = lane & 15, quad = lane >> 4;
  int e0 = (blockIdx.x*4 + wave)*16;
  if (e0 >= E) return;
  int arow = e0 + ln15;
  if (arow > E - 1) arow = E - 1;
  int ap = posOf[arow];
  s16x8 a = *(const s16x8*)(eap + (size_t)ap*EFEAT + quad*8);
  // hoist scattered pbuf loads for all 4 output rows
  int sArr[4], dArr[4];
  #pragma unroll
  for (int r = 0; r < 4; r++){
    int e = e0 + quad*4 + r;
    int ec = (e < E) ? e : E - 1;
    sArr[r] = srcA[ec]; dArr[r] = dstA[ec];
  }
  s16x8 pa[4], pb[4];
  #pragma unroll
  for (int r = 0; r < 4; r++){
    pa[r] = *(const s16x8*)(pbuf + (size_t)sArr[r]*256 + ln15*8);
    pb[r] = *(const s16x8*)(pbuf + (size_t)dArr[r]*256 + 128 + ln15*8);
  }
  f32x4 acc[8];
  #pragma unroll
  for (int c = 0; c < 8; c++){
    s16x8 b = *(const s16x8*)(Bh + ((size_t)c*64 + lane)*8);
    acc[c] = __builtin_amdgcn_mfma_f32_16x16x32_bf16(a, b, (f32x4)(0.f), 0, 0, 0);
  }
  float w2v[8];
  #pragma unroll
  for (int c = 0; c < 8; c++) w2v[c] = W2[c*16 + ln15];
  float res[4];
  #pragma unroll
  for (int r = 0; r < 4; r++){
    float sum = 0.f;
    #pragma unroll
    for (int c = 0; c < 8; c++){
      float q = acc[c][r] + bf2f((unsigned short)pa[r][c]) + bf2f((unsigned short)pb[r][c]);
      sum += fmaxf(q, 0.f) * w2v[c];
    }
    res[r] = sum;
  }
  #pragma unroll
  for (int r = 0; r < 4; r++){
    float v = res[r];
    v += __shfl_xor(v, 1, 64); v += __shfl_xor(v, 2, 64);
    v += __shfl_xor(v, 4, 64); v += __shfl_xor(v, 8, 64);
    res[r] = v;
  }
  if (ln15 == 0){
    float bb = b2[0];
    #pragma unroll
    for (int r = 0; r < 4; r++){
      int e = e0 + quad*4 + r;
      if (e < E) out[e] = res[r] + bb;
    }
  }
}

extern "C" void kernel_launch(void* const* d_in, const int* in_sizes, int n_in,
                              void* d_out, int out_size, void* d_ws, size_t ws_size,
                              hipStream_t stream){
  const float* x      = (const float*)d_in[0];
  const int*   eidx   = (const int*)d_in[1];
  const float* eattr  = (const float*)d_in[2];
  const float* gamma  = (const float*)d_in[3];
  const float* beta   = (const float*)d_in[4];
  const float* embW   = (const float*)d_in[5];
  const float* embB   = (const float*)d_in[6];
  const float* lnS    = (const float*)d_in[7];
  const float* lnB    = (const float*)d_in[8];
  const float* gatW   = (const float*)d_in[9];
  const float* attS   = (const float*)d_in[10];
  const float* attD   = (const float*)d_in[11];
  const float* gatWe  = (const float*)d_in[12];
  const float* attE   = (const float*)d_in[13];
  const float* gatB   = (const float*)d_in[14];
  const float* hW1    = (const float*)d_in[15];
  const float* hB1    = (const float*)d_in[16];
  const float* hW2    = (const float*)d_in[17];
  const float* hB2    = (const float*)d_in[18];
  float* out = (float*)d_out;

  int N = in_sizes[0] / DD;
  int E = in_sizes[1] / 2;
  int L = in_sizes[3] / DD;
  int Npad = (N + 63) & ~63;
  int nb = (N + SCHUNK - 1)/SCHUNK;

  const int* srcA = eidx;
  const int* dstA = eidx + E;

  float* ws = (float*)d_ws;
  float* ea_sum  = ws + 0;
  float* we_att  = ws + 64;
  float* al_self = ws + 1024;
  int* bsum      = (int*)(ws + 1280);
  int* boff      = (int*)(ws + 1536);
  float* ws_att  = ws + 2048;
  size_t o = 8192;
  int* deg    = (int*)(ws + o); o += N;
  int* offs   = (int*)(ws + o); o += N + 1;
  int* cursor = (int*)(ws + o); o += N;
  int* csrc   = (int*)(ws + o); o += E;
  int* posOf  = (int*)(ws + o); o += E;
  o = (o + 255) & ~(size_t)255;
  unsigned short* Bt  = (unsigned short*)(ws + o); o += (size_t)L*DD*HDIM/2;
  unsigned short* Btf = (unsigned short*)(ws + o); o += (size_t)L*DD*HDIM/2;
  unsigned short* Bh  = (unsigned short*)(ws + o); o += 8*64*8/2;
  unsigned short* Wte = (unsigned short*)(ws + o); o += DD*DD/2;
  unsigned short* Wtef= (unsigned short*)(ws + o); o += DD*DD/2;
  unsigned short* Bhd = (unsigned short*)(ws + o); o += 256*DD/2;
  unsigned short* Bhdf= (unsigned short*)(ws + o); o += 256*DD/2;
  unsigned short* xbf = (unsigned short*)(ws + o); o += (size_t)N*DD/2;
  unsigned short* hm_bf = (unsigned short*)(ws + o); o += (size_t)N*DD/2;
  float* al_s  = ws + o; o += (size_t)N*4;
  float* al_d  = ws + o; o += (size_t)N*4;
  unsigned short* eap = (unsigned short*)(ws + o); o += (size_t)E*EFEAT/2;
  float* ale   = ws + o; o += (size_t)L*E*4;
  unsigned short* z = (unsigned short*)(ws + o); o += (size_t)Npad*HDIM/2;
  unsigned short* hbf  = hm_bf;
  unsigned short* pbuf = z;

  hipMemsetAsync(ea_sum, 0, EFEAT*sizeof(float), stream);
  hipMemsetAsync(deg, 0, (size_t)N*sizeof(int), stream);
  hist_kernel<<<(E + 255)/256, 256, 0, stream>>>(dstA, deg, E);
  scan_part_kernel<<<nb, 256, 0, stream>>>(deg, bsum, N);
  scan_top_kernel<<<1, 64, 0, stream>>>(bsum, boff, offs, N, nb);
  scan_fin_kernel<<<nb, 256, 0, stream>>>(deg, boff, offs, cursor, N);
  scatter_kernel<<<(E + 255)/256, 256, 0, stream>>>(dstA, srcA, cursor, csrc, posOf, E);
  eap_bf16_kernel<<<(E*8 + N*DD/4 + 255)/256, 256, 0, stream>>>(
      eattr, posOf, eap, x, xbf, E, N*DD/4);
  fold_all_kernel<<<(L*DD*8 + L*EFEAT*NHEAD + 3)/4, 256, 0, stream>>>(
      gatW, attS, attD, gatWe, attE, ws_att, we_att, L);
  bt_prep_kernel<<<L*NHEAD*16, 256, 0, stream>>>(gatW, Bt, L*NHEAD);
  wprep_kernel<<<(DD*DD + 256*DD + 8*64*8 + 255)/256, 256, 0, stream>>>(
      embW, hW1, Wte, Bhd, Bh);
  ale_prep_kernel<<<(E + 255)/256, 256, 0, stream>>>(eap, we_att, ale, ea_sum, E, L);
  repack_all_kernel<<<(L*DD*HDIM/8 + DD*DD/8 + 256*DD/8 + L*NHEAD + 255)/256, 256, 0, stream>>>(
      Bt, Wte, Bhd, Btf, Wtef, Bhdf, we_att, ea_sum, 1.0f/(float)E, al_self, L);

  // embed + LN/FiLM/al (layer 0)
  gemm_fused_kernel<128,128><<<(N + 15)/16, 128, 0, stream>>>(
      xbf, Wtef, embB, 1.0f, 0, 0, lnS, lnB, gamma, beta, ws_att,
      hm_bf, al_s, al_d, nullptr, N);

  for (int l = 0; l < L; l++){
    aggregate4_kernel<<<N, 64, 0, stream>>>(hm_bf, ale + (size_t)l*E*4,
        al_s, al_d, al_self + (size_t)l*NHEAD, offs, csrc, z, N);
    if (l < L - 1){
      gemm_fused_kernel<512,128><<<(N + 15)/16, 128, 0, stream>>>(
          z, Btf + (size_t)l*DD*HDIM, gatB + (size_t)l*DD, 0.25f, 1, 0,
          lnS + (l+1)*DD, lnB + (l+1)*DD, gamma + (l+1)*DD, beta + (l+1)*DD,
          ws_att + (size_t)(l+1)*DD*8, hm_bf, al_s, al_d, nullptr, N);
    } else {
      gemm_fused_kernel<512,128><<<(N + 15)/16, 128, 0, stream>>>(
          z, Btf + (size_t)l*DD*HDIM, gatB + (size_t)l*DD, 0.25f, 1, 1,
          nullptr, nullptr, nullptr, nullptr, nullptr,
          nullptr, nullptr, nullptr, hbf, N);
    }
  }

  // head pre-projection: pbuf[N,256] = hbf @ [W1a|W1b] (+hB1 on cols<128)
  gemm_fused_kernel<128,256><<<(N + 15)/16, 128, 0, stream>>>(
      hbf, Bhdf, hB1, 1.0f, 0, 1, nullptr, nullptr, nullptr, nullptr, nullptr,
      nullptr, nullptr, nullptr, pbuf, N);

  head_mfma_kernel<<<(E + 63)/64, 256, 0, stream>>>(eap, posOf, Bh, pbuf,
      hW2, hB2, srcA, dstA, out, E);
}